// Round 24
// baseline (368.033 us; speedup 1.0000x reference)
//
#include <hip/hip_runtime.h>
#include <hip/hip_bf16.h>
#include <stdint.h>

#define B_TOT 131072
#define GAP_TAU 8e-4f

typedef short v8s __attribute__((ext_vector_type(8)));
typedef _Float16 v8h __attribute__((ext_vector_type(8)));
typedef float v4f __attribute__((ext_vector_type(4)));
typedef unsigned uv4 __attribute__((ext_vector_type(4)));
typedef unsigned uv2 __attribute__((ext_vector_type(2)));
typedef float fv4 __attribute__((ext_vector_type(4)));

__device__ __forceinline__ unsigned short f2bf(float f) {
    union { __hip_bfloat16 b; unsigned short s; } v;
    v.b = __float2bfloat16(f);
    return v.s;
}
__device__ __forceinline__ float bf2f(unsigned short s) {
    union { unsigned u; float f; } v; v.u = ((unsigned)s) << 16;
    return v.f;
}
__device__ __forceinline__ unsigned pack2(float lo, float hi) {
    return (unsigned)f2bf(lo) | ((unsigned)f2bf(hi) << 16);
}
// fp16 helpers (RNE)
__device__ __forceinline__ unsigned short f2h(float f) {
    union { _Float16 h; unsigned short s; } v;
    v.h = (_Float16)f;
    return v.s;
}
__device__ __forceinline__ float h2f(unsigned short s) {
    union { unsigned short s; _Float16 h; } v; v.s = s;
    return (float)v.h;
}
__device__ __forceinline__ unsigned pack2h(float lo, float hi) {
    return (unsigned)f2h(lo) | ((unsigned)f2h(hi) << 16);
}

// non-temporal helpers (pure cache hints; identical semantics)
__device__ __forceinline__ fv4 ntld_f4(const float* p) {
    return __builtin_nontemporal_load((const fv4*)p);
}
__device__ __forceinline__ v8h ntld_v8h(const unsigned short* p) {
    uv4 u = __builtin_nontemporal_load((const uv4*)p);
    union { uv4 u; v8h h; } c; c.u = u; return c.h;
}
__device__ __forceinline__ void ntst_u2(unsigned short* p, unsigned a, unsigned b) {
    uv2 u; u.x = a; u.y = b;
    __builtin_nontemporal_store(u, (uv2*)p);
}
__device__ __forceinline__ void ntst_f4(float* p, float x, float y, float z, float w) {
    fv4 f; f.x = x; f.y = y; f.z = z; f.w = w;
    __builtin_nontemporal_store(f, (fv4*)p);
}

// ---------------- K0: prep (weights swizzle + transposes + fcount zero) ----------------
// Weh/Weo frags are fp16 hi/lo (encoder now runs f16 MFMA); Wdh/Wdo stay bf16 (decoder).
__global__ void k_prep(const float* __restrict__ W_dh,      // [512][64]
                       const float* __restrict__ b_do,
                       const float* __restrict__ dec_b,
                       const float* __restrict__ pre_bias,
                       const float* __restrict__ W_do,
                       const float* __restrict__ W_eh,
                       const float* __restrict__ W_eo,
                       unsigned short* __restrict__ WdhB,    // hd-GEMM W-frags [32ht][2kc][64][8]
                       float* __restrict__ bias3,
                       unsigned short* __restrict__ Wdo_frag,
                       unsigned short* __restrict__ WehHi,
                       unsigned short* __restrict__ WehLo,
                       unsigned short* __restrict__ WeoHi,
                       unsigned short* __restrict__ WeoLo,
                       float* __restrict__ WehT,             // fp32 [256][512]
                       float* __restrict__ WeoT,             // fp32 [512][64]
                       float* __restrict__ spars_out,
                       int* __restrict__ fcount)
{
    int t = blockIdx.x * blockDim.x + threadIdx.x;
    int nthr = gridDim.x * blockDim.x;
    for (int g = t; g < 32 * 2 * 64; g += nthr) {
        int lane = g & 63;
        int rem = g >> 6;
        int kc = rem & 1, ht = rem >> 1;
        int h = ht * 16 + (lane & 15);
        int l = kc * 32 + (lane >> 4) * 8;
        const float* src = &W_dh[(size_t)h * 64 + l];
        unsigned short* dst = &WdhB[(size_t)g * 8];
        #pragma unroll
        for (int i = 0; i < 8; i++) dst[i] = f2bf(src[i]);
    }
    for (int g = t; g < 16384; g += nthr) {     // Wdo B-frag (bf16)
        int lane = g & 63;
        int q = g >> 6;
        int nt = q >> 4, kc = q & 15;
        int col = nt * 16 + (lane & 15);
        int kbase = kc * 32 + (lane >> 4) * 8;
        const float* src = &W_do[(size_t)col * 512 + kbase];
        unsigned short* dst = &Wdo_frag[(size_t)g * 8];
        #pragma unroll
        for (int i = 0; i < 8; i++) dst[i] = f2bf(src[i]);
    }
    for (int g = t; g < 32 * 8 * 64; g += nthr) {   // W_eh hi/lo A-frag (fp16)
        int lane = g & 63;
        int rem = g >> 6;
        int kcg = rem & 7, ct = rem >> 3;
        int c = ct * 16 + (lane & 15);
        int k = kcg * 32 + (lane >> 4) * 8;
        const float* src = &W_eh[(size_t)c * 256 + k];
        #pragma unroll
        for (int i = 0; i < 8; i++) {
            unsigned short hi = f2h(src[i]);
            WehHi[(size_t)g * 8 + i] = hi;
            WehLo[(size_t)g * 8 + i] = f2h(src[i] - h2f(hi));
        }
    }
    for (int g = t; g < 4 * 16 * 64; g += nthr) {   // W_eo hi/lo A-frag (fp16)
        int lane = g & 63;
        int rem = g >> 6;
        int kcg = rem & 15, lt = rem >> 4;
        int l = lt * 16 + (lane & 15);
        int k = kcg * 32 + (lane >> 4) * 8;
        const float* src = &W_eo[(size_t)l * 512 + k];
        #pragma unroll
        for (int i = 0; i < 8; i++) {
            unsigned short hi = f2h(src[i]);
            WeoHi[(size_t)g * 8 + i] = hi;
            WeoLo[(size_t)g * 8 + i] = f2h(src[i] - h2f(hi));
        }
    }
    for (int i = t; i < 256 * 512; i += nthr) {     // WehT[k][j] = W_eh[j][k]
        int k = i >> 9, j = i & 511;
        WehT[i] = W_eh[(size_t)j * 256 + k];
    }
    for (int i = t; i < 512 * 64; i += nthr) {      // WeoT[k][l] = W_eo[l][k]
        int k = i >> 6, l = i & 63;
        WeoT[i] = W_eo[(size_t)l * 512 + k];
    }
    if (t < 256) bias3[t] = b_do[t] + dec_b[t] + pre_bias[t];
    if (t == 0) { spars_out[0] = 5.0f / 64.0f; *fcount = 0; }
}

// h plane OCTET layout (SINGLE fp16 plane): element H(row,k) =
//   ((rowtile*64 + k/8)*16 + row%16)*8 + k%8

// ---------------- K1: h = relu((x-pb) @ W_eh^T + b_eh), split-fp16 MFMA ----------------
// 2-pass column split; fp16 hi/lo x and W; single fp16 h plane out.
__global__ __launch_bounds__(512, 4)
void k_enc1(const float* __restrict__ x,
            const float* __restrict__ pre_bias,
            const unsigned short* __restrict__ WehHi,
            const unsigned short* __restrict__ WehLo,
            const float* __restrict__ b_eh,
            unsigned short* __restrict__ hH)    // octet layout, fp16
{
    __shared__ __align__(16) unsigned short aH[64 * 256];  // 32 KB, swizzled rows
    __shared__ __align__(16) unsigned short aL[64 * 256];  // 32 KB
    const int t    = threadIdx.x;
    const int lane = t & 63;
    const int w    = t >> 6;        // 0..7
    const int rb   = blockIdx.x * 64;

    #pragma unroll
    for (int i = 0; i < 4; i++) {
        const int f    = t + i * 512;       // 0..2047
        const int srow = f >> 5;            // 0..63
        const int kc   = (f >> 2) & 7;      // 0..7
        const int skq  = f & 3;             // 0..3
        const float* xp = &x[(size_t)(rb + srow) * 256 + kc * 32 + skq * 8];
        const float* pp = &pre_bias[kc * 32 + skq * 8];
        const fv4 v0 = ntld_f4(xp);
        const fv4 v1 = ntld_f4(xp + 4);
        const float4 p0 = *reinterpret_cast<const float4*>(pp);
        const float4 p1 = *reinterpret_cast<const float4*>(pp + 4);
        float fv[8] = {v0.x - p0.x, v0.y - p0.y, v0.z - p0.z, v0.w - p0.w,
                       v1.x - p1.x, v1.y - p1.y, v1.z - p1.z, v1.w - p1.w};
        unsigned hi2[4], lo2[4];
        #pragma unroll
        for (int q = 0; q < 4; q++) {
            unsigned short h0 = f2h(fv[q * 2]), h1 = f2h(fv[q * 2 + 1]);
            hi2[q] = (unsigned)h0 | ((unsigned)h1 << 16);
            lo2[q] = pack2h(fv[q * 2] - h2f(h0), fv[q * 2 + 1] - h2f(h1));
        }
        const int off = srow * 512 + ((kc * 64 + skq * 16) ^ ((srow & 7) << 4));
        *reinterpret_cast<uint4*>((char*)aH + off) = *reinterpret_cast<uint4*>(hi2);
        *reinterpret_cast<uint4*>((char*)aL + off) = *reinterpret_cast<uint4*>(lo2);
    }
    __syncthreads();

    const int rt0 = rb >> 4;
    const int q   = lane >> 4;

    #pragma unroll 1
    for (int pass = 0; pass < 2; ++pass) {
        const int ct0 = w * 4 + pass * 2;

        v4f acc[4][2];
        #pragma unroll
        for (int i = 0; i < 4; i++)
            #pragma unroll
            for (int j = 0; j < 2; j++) acc[i][j] = (v4f){0.f, 0.f, 0.f, 0.f};

        #pragma unroll 4
        for (int kc = 0; kc < 8; ++kc) {
            v8h wh[2], wl[2];
            #pragma unroll
            for (int ntl = 0; ntl < 2; ntl++) {
                const size_t idx = ((size_t)((ct0 + ntl) * 8 + kc) * 64 + lane) * 8;
                wh[ntl] = *reinterpret_cast<const v8h*>(&WehHi[idx]);
                wl[ntl] = *reinterpret_cast<const v8h*>(&WehLo[idx]);
            }
            v8h ah[4], al[4];
            #pragma unroll
            for (int mt = 0; mt < 4; mt++) {
                const int row = mt * 16 + (lane & 15);
                const int off = row * 512 + ((kc * 64 + (lane >> 4) * 16) ^ ((row & 7) << 4));
                ah[mt] = *reinterpret_cast<const v8h*>((const char*)aH + off);
                al[mt] = *reinterpret_cast<const v8h*>((const char*)aL + off);
            }
            #pragma unroll
            for (int mt = 0; mt < 4; mt++) {
                #pragma unroll
                for (int ntl = 0; ntl < 2; ntl++) {
                    acc[mt][ntl] = __builtin_amdgcn_mfma_f32_16x16x32_f16(wh[ntl], ah[mt], acc[mt][ntl], 0, 0, 0);
                    acc[mt][ntl] = __builtin_amdgcn_mfma_f32_16x16x32_f16(wl[ntl], ah[mt], acc[mt][ntl], 0, 0, 0);
                    acc[mt][ntl] = __builtin_amdgcn_mfma_f32_16x16x32_f16(wh[ntl], al[mt], acc[mt][ntl], 0, 0, 0);
                }
            }
        }
        // epilogue for this pass's 2 col-tiles: single fp16 plane, nt stores
        #pragma unroll
        for (int mt = 0; mt < 4; mt++) {
            #pragma unroll
            for (int ntl = 0; ntl < 2; ntl++) {
                const int ct = ct0 + ntl;
                const int c  = ct * 16 + q * 4;
                const float4 be = *reinterpret_cast<const float4*>(&b_eh[c]);
                float h0 = fmaxf(acc[mt][ntl][0] + be.x, 0.f);
                float h1 = fmaxf(acc[mt][ntl][1] + be.y, 0.f);
                float h2 = fmaxf(acc[mt][ntl][2] + be.z, 0.f);
                float h3 = fmaxf(acc[mt][ntl][3] + be.w, 0.f);
                const unsigned phx = pack2h(h0, h1);
                const unsigned phy = pack2h(h2, h3);
                const int oct = ct * 2 + (q >> 1);
                const size_t base = (((size_t)(rt0 + mt) * 64 + oct) * 16 + (lane & 15)) * 8 + (q & 1) * 4;
                ntst_u2(&hH[base], phx, phy);
            }
        }
    }
}

// ---------------- K2: pre_act (fp16 MFMA, 2 products); top-5; gap-flag; outputs ----------------
// 128 rows/block; wave w owns row-tiles {2w, 2w+1}; single fp16 h plane.
__global__ __launch_bounds__(256, 4)
void k_enc2_topk(const unsigned short* __restrict__ hH,    // octet layout, fp16
                 const unsigned short* __restrict__ WeoHi,
                 const unsigned short* __restrict__ WeoLo,
                 const float* __restrict__ b_eo,
                 const float* __restrict__ lat_b,
                 float* __restrict__ pre_out,
                 float* __restrict__ mask_out,
                 float* __restrict__ sl_out,
                 int*   __restrict__ fcount,
                 int*   __restrict__ flist)
{
    __shared__ float pa[128][68];
    __shared__ unsigned long long mbits[128];
    const int t    = threadIdx.x;
    const int lane = t & 63;
    const int w    = t >> 6;
    const int rb   = blockIdx.x * 128;
    const int rtA  = (rb >> 4) + w * 2;
    const int rtB  = rtA + 1;

    v4f acc[2][4];
    #pragma unroll
    for (int s = 0; s < 2; s++)
        #pragma unroll
        for (int i = 0; i < 4; i++) acc[s][i] = (v4f){0.f, 0.f, 0.f, 0.f};

    #pragma unroll 4
    for (int kcl = 0; kcl < 16; ++kcl) {
        const size_t baseA = ((size_t)(rtA * 64 + kcl * 4 + (lane >> 4)) * 16 + (lane & 15)) * 8;
        const size_t baseB = ((size_t)(rtB * 64 + kcl * 4 + (lane >> 4)) * 16 + (lane & 15)) * 8;
        const v8h hA = ntld_v8h(&hH[baseA]);
        const v8h hB = ntld_v8h(&hH[baseB]);
        #pragma unroll
        for (int lt = 0; lt < 4; lt++) {
            const size_t idx = ((size_t)(lt * 16 + kcl) * 64 + lane) * 8;
            const v8h wh = *reinterpret_cast<const v8h*>(&WeoHi[idx]);
            const v8h wl = *reinterpret_cast<const v8h*>(&WeoLo[idx]);
            acc[0][lt] = __builtin_amdgcn_mfma_f32_16x16x32_f16(wh, hA, acc[0][lt], 0, 0, 0);
            acc[0][lt] = __builtin_amdgcn_mfma_f32_16x16x32_f16(wl, hA, acc[0][lt], 0, 0, 0);
            acc[1][lt] = __builtin_amdgcn_mfma_f32_16x16x32_f16(wh, hB, acc[1][lt], 0, 0, 0);
            acc[1][lt] = __builtin_amdgcn_mfma_f32_16x16x32_f16(wl, hB, acc[1][lt], 0, 0, 0);
        }
    }
    #pragma unroll
    for (int s = 0; s < 2; s++) {
        const int row = w * 32 + s * 16 + (lane & 15);
        #pragma unroll
        for (int lt = 0; lt < 4; lt++) {
            const int l0 = lt * 16 + ((lane >> 4) << 2);
            const float4 be = *reinterpret_cast<const float4*>(&b_eo[l0]);
            const float4 lb = *reinterpret_cast<const float4*>(&lat_b[l0]);
            float4 o;
            o.x = acc[s][lt][0] + be.x + lb.x;
            o.y = acc[s][lt][1] + be.y + lb.y;
            o.z = acc[s][lt][2] + be.z + lb.z;
            o.w = acc[s][lt][3] + be.w + lb.w;
            *reinterpret_cast<float4*>(&pa[row][l0]) = o;
        }
    }
    __syncthreads();
    if (t < 128) {
        int r = t;
        unsigned long long used = 0ULL;
        float bv[5];
        #pragma unroll
        for (int p = 0; p < 5; p++) {
            float best = -3.402823466e38f; int bidx = 0;
            for (int j = 0; j < 64; j++) {
                float v = pa[r][j];
                if (!((used >> j) & 1ULL) && v > best) { best = v; bidx = j; }
            }
            used |= 1ULL << bidx;
            bv[p] = best;
        }
        mbits[r] = used;
        float v6 = -3.402823466e38f;
        for (int j = 0; j < 64; j++) {
            float v = pa[r][j];
            if (!((used >> j) & 1ULL) && v > v6) v6 = v;
        }
        if (bv[4] - v6 < GAP_TAU) {
            int slot = atomicAdd(fcount, 1);
            flist[slot] = rb + r;
        }
    }
    __syncthreads();
    {
        const int c = (t & 15) * 4;
        #pragma unroll
        for (int pass = 0; pass < 8; pass++) {
            const int row = pass * 16 + (t >> 4);
            const size_t gr = (size_t)(rb + row);
            const unsigned long long bits = mbits[row];
            const float p0 = pa[row][c + 0], p1 = pa[row][c + 1];
            const float p2 = pa[row][c + 2], p3 = pa[row][c + 3];
            const float m0 = (float)((bits >> (c + 0)) & 1ULL);
            const float m1 = (float)((bits >> (c + 1)) & 1ULL);
            const float m2 = (float)((bits >> (c + 2)) & 1ULL);
            const float m3 = (float)((bits >> (c + 3)) & 1ULL);
            ntst_f4(&pre_out[gr * 64 + c],  p0, p1, p2, p3);
            ntst_f4(&mask_out[gr * 64 + c], m0, m1, m2, m3);
            ntst_f4(&sl_out[gr * 64 + c],   m0 * p0, m1 * p1, m2 * p2, m3 * p3);
        }
    }
}

// ---------------- K2b: fp32 exact repair of gap-flagged rows ----------------
__global__ __launch_bounds__(256)
void k_repair(const float* __restrict__ x,
              const float* __restrict__ pre_bias,
              const float* __restrict__ WehT,     // [256][512] fp32 transposed
              const float* __restrict__ b_eh,
              const float* __restrict__ WeoT,     // [512][64] fp32 transposed
              const float* __restrict__ b_eo,
              const float* __restrict__ lat_b,
              const int* __restrict__ fcount,
              const int* __restrict__ flist,
              float* __restrict__ pre_out,
              float* __restrict__ mask_out,
              float* __restrict__ sl_out)
{
    __shared__ float xs[256];
    __shared__ float hs[512];
    __shared__ float part[64][4];
    const int t = threadIdx.x;
    const int n = *fcount;
    #pragma unroll 1
    for (int it = blockIdx.x; it < n; it += gridDim.x) {
        const int r = flist[it];
        xs[t] = x[(size_t)r * 256 + t] - pre_bias[t];
        __syncthreads();
        {
            float a0 = 0.f, a1 = 0.f;
            #pragma unroll 8
            for (int k = 0; k < 256; ++k) {
                const float xk = xs[k];
                a0 = fmaf(WehT[(size_t)k * 512 + t], xk, a0);
                a1 = fmaf(WehT[(size_t)k * 512 + t + 256], xk, a1);
            }
            hs[t]       = fmaxf(a0 + b_eh[t], 0.f);
            hs[t + 256] = fmaxf(a1 + b_eh[t + 256], 0.f);
        }
        __syncthreads();
        {
            const int l = t & 63, q = t >> 6;
            float acc = 0.f;
            const int k0 = q * 128;
            #pragma unroll 8
            for (int k = k0; k < k0 + 128; ++k)
                acc = fmaf(WeoT[(size_t)k * 64 + l], hs[k], acc);
            part[l][q] = acc;
        }
        __syncthreads();
        if (t < 64) {
            const float v = ((part[t][0] + part[t][1]) + (part[t][2] + part[t][3]))
                            + b_eo[t] + lat_b[t];
            unsigned long long used = 0ULL;
            #pragma unroll
            for (int p = 0; p < 5; p++) {
                float cand = ((used >> t) & 1ULL) ? -3.402823466e38f : v;
                float m = cand;
                #pragma unroll
                for (int off = 1; off < 64; off <<= 1)
                    m = fmaxf(m, __shfl_xor(m, off));
                const unsigned long long msk = __ballot(cand == m);
                const int idx = __ffsll((long long)msk) - 1;
                used |= 1ULL << idx;
            }
            const size_t gr = (size_t)r;
            const float mb = (float)((used >> t) & 1ULL);
            pre_out[gr * 64 + t]  = v;
            mask_out[gr * 64 + t] = mb;
            sl_out[gr * 64 + t]   = mb * v;
        }
        __syncthreads();
    }
}

// ---------------- K3 phase 1: hd-tile GEMM (swapped operands -> A-frag-native D) ----------------
__device__ __forceinline__ void hd_phase1(unsigned short* __restrict__ buf,
                                          const unsigned short* __restrict__ slA,
                                          const unsigned short* __restrict__ WdhB,
                                          const float* __restrict__ b_dh,
                                          int c, int w, int lane)
{
    v4f ah[2][4];
    #pragma unroll
    for (int htl = 0; htl < 2; htl++) {
        const int h0 = (c * 8 + w * 2 + htl) * 16 + ((lane >> 4) << 2);
        const float4 bd = *reinterpret_cast<const float4*>(&b_dh[h0]);
        #pragma unroll
        for (int mt = 0; mt < 4; mt++) ah[htl][mt] = (v4f){bd.x, bd.y, bd.z, bd.w};
    }
    #pragma unroll
    for (int kc = 0; kc < 2; kc++) {
        v8s sa[4];
        #pragma unroll
        for (int mt = 0; mt < 4; mt++)
            sa[mt] = *reinterpret_cast<const v8s*>(&slA[((kc * 4 + mt) * 64 + lane) * 8]);
        #pragma unroll
        for (int htl = 0; htl < 2; htl++) {
            const int ht = c * 8 + w * 2 + htl;
            const v8s wb = *reinterpret_cast<const v8s*>(&WdhB[((size_t)(ht * 2 + kc) * 64 + lane) * 8]);
            #pragma unroll
            for (int mt = 0; mt < 4; mt++)
                ah[htl][mt] = __builtin_amdgcn_mfma_f32_16x16x32_bf16(wb, sa[mt], ah[htl][mt], 0, 0, 0);
        }
    }
    #pragma unroll
    for (int htl = 0; htl < 2; htl++) {
        const int hbase = (w * 2 + htl) * 16 + ((lane >> 4) << 2);
        const int kcgl  = hbase >> 5;
        const int lp    = (((hbase & 31) >> 3) << 4) + (lane & 15);
        const int ii    = hbase & 7;
        #pragma unroll
        for (int mt = 0; mt < 4; mt++) {
            uint2 o;
            o.x = pack2(fmaxf(ah[htl][mt][0], 0.f), fmaxf(ah[htl][mt][1], 0.f));
            o.y = pack2(fmaxf(ah[htl][mt][2], 0.f), fmaxf(ah[htl][mt][3], 0.f));
            *reinterpret_cast<uint2*>(&buf[((kcgl * 4 + mt) * 64 + lp) * 8 + ii]) = o;
        }
    }
}

// ---------------- K3: recon fully via MFMA, double-buffered hd, 1 barrier/chunk ----------------
__global__ __launch_bounds__(256)
void k_dec(const float* __restrict__ sl,              // [B][64] f32 (post-repair)
           const float* __restrict__ b_dh,            // [512]
           const unsigned short* __restrict__ WdhB,
           const unsigned short* __restrict__ Wdo_frag,
           const float* __restrict__ bias3,
           float* __restrict__ recon)                 // global [B][256]
{
    __shared__ __align__(16) unsigned short slA[2 * 4 * 64 * 8];      // 4 KB
    __shared__ __align__(16) unsigned short hdA[2][4 * 4 * 64 * 8];   // 2 x 16 KB
    const int t    = threadIdx.x;
    const int rb   = blockIdx.x * 64;
    const int lane = t & 63;
    const int w    = t >> 6;

    {
        const int row = t >> 2;
        const int seg = (t & 3) * 16;
        const float* sp = &sl[(size_t)(rb + row) * 64 + seg];
        const int mt = row >> 4;
        #pragma unroll
        for (int q = 0; q < 4; q++) {
            const fv4 v = ntld_f4(sp + q * 4);
            const float vals[4] = {v.x, v.y, v.z, v.w};
            #pragma unroll
            for (int e = 0; e < 4; e++) {
                const int k  = seg + q * 4 + e;
                const int kc = k >> 5;
                const int lp = ((k & 31) >> 3) * 16 + (row & 15);
                slA[((kc * 4 + mt) * 64 + lp) * 8 + (k & 7)] = f2bf(vals[e]);
            }
        }
    }
    __syncthreads();

    const int g  = w >> 1;      // main-GEMM row-group
    const int ch = w & 1;       // main-GEMM col-half

    v4f accM[2][8];
    #pragma unroll
    for (int s = 0; s < 2; s++)
        #pragma unroll
        for (int n = 0; n < 8; n++) accM[s][n] = (v4f){0.f, 0.f, 0.f, 0.f};

    hd_phase1(hdA[0], slA, WdhB, b_dh, 0, w, lane);
    __syncthreads();

    #pragma unroll 1
    for (int c = 0; c < 4; ++c) {
        if (c < 3)
            hd_phase1(hdA[(c + 1) & 1], slA, WdhB, b_dh, c + 1, w, lane);
        const unsigned short* buf = hdA[c & 1];
        #pragma unroll
        for (int kcgl = 0; kcgl < 4; ++kcgl) {
            const int kcg = c * 4 + kcgl;
            const v8s af0 = *reinterpret_cast<const v8s*>(&buf[((kcgl * 4 + g * 2 + 0) * 64 + lane) * 8]);
            const v8s af1 = *reinterpret_cast<const v8s*>(&buf[((kcgl * 4 + g * 2 + 1) * 64 + lane) * 8]);
            #pragma unroll
            for (int ntl = 0; ntl < 8; ntl++) {
                const int ntg = ch * 8 + ntl;
                const v8s bf = *reinterpret_cast<const v8s*>(
                    Wdo_frag + ((size_t)(ntg * 16 + kcg) * 64 + lane) * 8);
                accM[0][ntl] = __builtin_amdgcn_mfma_f32_16x16x32_bf16(af0, bf, accM[0][ntl], 0, 0, 0);
                accM[1][ntl] = __builtin_amdgcn_mfma_f32_16x16x32_bf16(af1, bf, accM[1][ntl], 0, 0, 0);
            }
        }
        __syncthreads();
    }
    #pragma unroll
    for (int s = 0; s < 2; s++) {
        const int rowbase = rb + (g * 2 + s) * 16;
        #pragma unroll
        for (int ntl = 0; ntl < 8; ntl++) {
            const int col = ch * 128 + ntl * 16 + (lane & 15);
            const float bz = bias3[col];
            #pragma unroll
            for (int j = 0; j < 4; j++) {
                const size_t row = (size_t)(rowbase + (lane >> 4) * 4 + j);
                __builtin_nontemporal_store(accM[s][ntl][j] + bz, &recon[row * 256 + col]);
            }
        }
    }
}

// ---------------- host ----------------
extern "C" void kernel_launch(void* const* d_in, const int* in_sizes, int n_in,
                              void* d_out, int out_size, void* d_ws, size_t ws_size,
                              hipStream_t stream)
{
    const float* x        = (const float*)d_in[0];
    const float* pre_bias = (const float*)d_in[1];
    const float* W_eh     = (const float*)d_in[2];
    const float* b_eh     = (const float*)d_in[3];
    const float* W_eo     = (const float*)d_in[4];
    const float* b_eo     = (const float*)d_in[5];
    const float* lat_b    = (const float*)d_in[6];
    const float* W_dh     = (const float*)d_in[7];
    const float* b_dh     = (const float*)d_in[8];
    const float* W_do     = (const float*)d_in[9];
    const float* b_do     = (const float*)d_in[10];
    const float* dec_b    = (const float*)d_in[11];

    float* out = (float*)d_out;
    float* recon_out = out;
    float* sl_out    = out + (size_t)B_TOT * 256;
    float* pre_out   = sl_out + (size_t)B_TOT * 64;
    float* mask_out  = pre_out + (size_t)B_TOT * 64;
    float* spars_out = mask_out + (size_t)B_TOT * 64;

    char* ws = (char*)d_ws;
    unsigned short* WdhB  = (unsigned short*)ws;            // 64 KB (of 128 KB slot)
    float* bias3          = (float*)(ws + 131072);
    unsigned short* WdoF  = (unsigned short*)(ws + 132096);
    unsigned short* WehHi = (unsigned short*)(ws + 394240);
    unsigned short* WehLo = (unsigned short*)(ws + 656384);
    unsigned short* WeoHi = (unsigned short*)(ws + 918528);
    unsigned short* WeoLo = (unsigned short*)(ws + 984064);
    int* fcount           = (int*)(ws + 1049600);
    int* flist            = (int*)(ws + 1049664);           // 512 KB
    float* WehT           = (float*)(ws + 1573952);         // 512 KB
    float* WeoT           = (float*)(ws + 2098240);         // 128 KB
    unsigned short* hH    = (unsigned short*)(ws + 2229312);  // B*512 fp16 = 134 MB

    k_prep<<<32, 256, 0, stream>>>(W_dh, b_do, dec_b, pre_bias, W_do, W_eh, W_eo,
                                   WdhB, bias3, WdoF, WehHi, WehLo, WeoHi, WeoLo,
                                   WehT, WeoT, spars_out, fcount);

    k_enc1<<<B_TOT / 64, 512, 0, stream>>>(x, pre_bias, WehHi, WehLo, b_eh, hH);

    k_enc2_topk<<<B_TOT / 128, 256, 0, stream>>>(hH, WeoHi, WeoLo, b_eo, lat_b,
                                                 pre_out, mask_out, sl_out,
                                                 fcount, flist);

    k_repair<<<1024, 256, 0, stream>>>(x, pre_bias, WehT, b_eh, WeoT, b_eo, lat_b,
                                       fcount, flist, pre_out, mask_out, sl_out);

    k_dec<<<B_TOT / 64, 256, 0, stream>>>(sl_out, b_dh, WdhB, WdoF, bias3, recon_out);
}

// Round 25
// 351.913 us; speedup vs baseline: 1.0458x; 1.0458x over previous
//
#include <hip/hip_runtime.h>
#include <hip/hip_bf16.h>
#include <stdint.h>

#define B_TOT 131072
#define GAP_TAU 2.5e-4f

typedef short v8s __attribute__((ext_vector_type(8)));
typedef float v4f __attribute__((ext_vector_type(4)));
typedef unsigned uv4 __attribute__((ext_vector_type(4)));
typedef unsigned uv2 __attribute__((ext_vector_type(2)));
typedef float fv4 __attribute__((ext_vector_type(4)));

__device__ __forceinline__ unsigned short f2bf(float f) {
    union { __hip_bfloat16 b; unsigned short s; } v;
    v.b = __float2bfloat16(f);
    return v.s;
}
__device__ __forceinline__ float bf2f(unsigned short s) {
    union { unsigned u; float f; } v; v.u = ((unsigned)s) << 16;
    return v.f;
}
__device__ __forceinline__ unsigned pack2(float lo, float hi) {
    return (unsigned)f2bf(lo) | ((unsigned)f2bf(hi) << 16);
}

// non-temporal helpers (pure cache hints; identical semantics)
__device__ __forceinline__ fv4 ntld_f4(const float* p) {
    return __builtin_nontemporal_load((const fv4*)p);
}
__device__ __forceinline__ v8s ntld_v8s(const unsigned short* p) {
    uv4 u = __builtin_nontemporal_load((const uv4*)p);
    union { uv4 u; v8s s; } c; c.u = u; return c.s;
}
__device__ __forceinline__ void ntst_u2(unsigned short* p, unsigned a, unsigned b) {
    uv2 u; u.x = a; u.y = b;
    __builtin_nontemporal_store(u, (uv2*)p);
}
__device__ __forceinline__ void ntst_f4(float* p, float x, float y, float z, float w) {
    fv4 f; f.x = x; f.y = y; f.z = z; f.w = w;
    __builtin_nontemporal_store(f, (fv4*)p);
}

// ---------------- K0: prep (weights swizzle + transposes + fcount zero) ----------------
__global__ void k_prep(const float* __restrict__ W_dh,      // [512][64]
                       const float* __restrict__ b_do,
                       const float* __restrict__ dec_b,
                       const float* __restrict__ pre_bias,
                       const float* __restrict__ W_do,
                       const float* __restrict__ W_eh,
                       const float* __restrict__ W_eo,
                       unsigned short* __restrict__ WdhB,    // hd-GEMM W-frags [32ht][2kc][64][8]
                       float* __restrict__ bias3,
                       unsigned short* __restrict__ Wdo_frag,
                       unsigned short* __restrict__ WehHi,
                       unsigned short* __restrict__ WehLo,
                       unsigned short* __restrict__ WeoHi,
                       unsigned short* __restrict__ WeoLo,
                       float* __restrict__ WehT,             // fp32 [256][512]
                       float* __restrict__ WeoT,             // fp32 [512][64]
                       float* __restrict__ spars_out,
                       int* __restrict__ fcount)
{
    int t = blockIdx.x * blockDim.x + threadIdx.x;
    int nthr = gridDim.x * blockDim.x;
    for (int g = t; g < 32 * 2 * 64; g += nthr) {
        int lane = g & 63;
        int rem = g >> 6;
        int kc = rem & 1, ht = rem >> 1;
        int h = ht * 16 + (lane & 15);
        int l = kc * 32 + (lane >> 4) * 8;
        const float* src = &W_dh[(size_t)h * 64 + l];
        unsigned short* dst = &WdhB[(size_t)g * 8];
        #pragma unroll
        for (int i = 0; i < 8; i++) dst[i] = f2bf(src[i]);
    }
    for (int g = t; g < 16384; g += nthr) {     // Wdo B-frag
        int lane = g & 63;
        int q = g >> 6;
        int nt = q >> 4, kc = q & 15;
        int col = nt * 16 + (lane & 15);
        int kbase = kc * 32 + (lane >> 4) * 8;
        const float* src = &W_do[(size_t)col * 512 + kbase];
        unsigned short* dst = &Wdo_frag[(size_t)g * 8];
        #pragma unroll
        for (int i = 0; i < 8; i++) dst[i] = f2bf(src[i]);
    }
    for (int g = t; g < 32 * 8 * 64; g += nthr) {   // W_eh hi/lo A-frag
        int lane = g & 63;
        int rem = g >> 6;
        int kcg = rem & 7, ct = rem >> 3;
        int c = ct * 16 + (lane & 15);
        int k = kcg * 32 + (lane >> 4) * 8;
        const float* src = &W_eh[(size_t)c * 256 + k];
        #pragma unroll
        for (int i = 0; i < 8; i++) {
            unsigned short hi = f2bf(src[i]);
            WehHi[(size_t)g * 8 + i] = hi;
            WehLo[(size_t)g * 8 + i] = f2bf(src[i] - bf2f(hi));
        }
    }
    for (int g = t; g < 4 * 16 * 64; g += nthr) {   // W_eo hi/lo A-frag
        int lane = g & 63;
        int rem = g >> 6;
        int kcg = rem & 15, lt = rem >> 4;
        int l = lt * 16 + (lane & 15);
        int k = kcg * 32 + (lane >> 4) * 8;
        const float* src = &W_eo[(size_t)l * 512 + k];
        #pragma unroll
        for (int i = 0; i < 8; i++) {
            unsigned short hi = f2bf(src[i]);
            WeoHi[(size_t)g * 8 + i] = hi;
            WeoLo[(size_t)g * 8 + i] = f2bf(src[i] - bf2f(hi));
        }
    }
    for (int i = t; i < 256 * 512; i += nthr) {     // WehT[k][j] = W_eh[j][k]
        int k = i >> 9, j = i & 511;
        WehT[i] = W_eh[(size_t)j * 256 + k];
    }
    for (int i = t; i < 512 * 64; i += nthr) {      // WeoT[k][l] = W_eo[l][k]
        int k = i >> 6, l = i & 63;
        WeoT[i] = W_eo[(size_t)l * 512 + k];
    }
    if (t < 256) bias3[t] = b_do[t] + dec_b[t] + pre_bias[t];
    if (t == 0) { spars_out[0] = 5.0f / 64.0f; *fcount = 0; }
}

// h planes OCTET layout: element H(row,k) = ((rowtile*64 + k/8)*16 + row%16)*8 + k%8

// ---------------- K1: h = relu((x-pb) @ W_eh^T + b_eh), split-bf16 MFMA ----------------
// 2-pass column split; native cvt; nt streaming loads/stores; math bit-identical.
__global__ __launch_bounds__(512, 4)
void k_enc1(const float* __restrict__ x,
            const float* __restrict__ pre_bias,
            const unsigned short* __restrict__ WehHi,
            const unsigned short* __restrict__ WehLo,
            const float* __restrict__ b_eh,
            unsigned short* __restrict__ hHi,   // octet layout
            unsigned short* __restrict__ hLo)
{
    __shared__ __align__(16) unsigned short aH[64 * 256];  // 32 KB, swizzled rows
    __shared__ __align__(16) unsigned short aL[64 * 256];  // 32 KB
    const int t    = threadIdx.x;
    const int lane = t & 63;
    const int w    = t >> 6;        // 0..7
    const int rb   = blockIdx.x * 64;

    #pragma unroll
    for (int i = 0; i < 4; i++) {
        const int f    = t + i * 512;       // 0..2047
        const int srow = f >> 5;            // 0..63
        const int kc   = (f >> 2) & 7;      // 0..7
        const int skq  = f & 3;             // 0..3
        const float* xp = &x[(size_t)(rb + srow) * 256 + kc * 32 + skq * 8];
        const float* pp = &pre_bias[kc * 32 + skq * 8];
        const fv4 v0 = ntld_f4(xp);
        const fv4 v1 = ntld_f4(xp + 4);
        const float4 p0 = *reinterpret_cast<const float4*>(pp);
        const float4 p1 = *reinterpret_cast<const float4*>(pp + 4);
        float fv[8] = {v0.x - p0.x, v0.y - p0.y, v0.z - p0.z, v0.w - p0.w,
                       v1.x - p1.x, v1.y - p1.y, v1.z - p1.z, v1.w - p1.w};
        unsigned hi2[4], lo2[4];
        #pragma unroll
        for (int q = 0; q < 4; q++) {
            unsigned short h0 = f2bf(fv[q * 2]), h1 = f2bf(fv[q * 2 + 1]);
            hi2[q] = (unsigned)h0 | ((unsigned)h1 << 16);
            lo2[q] = pack2(fv[q * 2] - bf2f(h0), fv[q * 2 + 1] - bf2f(h1));
        }
        const int off = srow * 512 + ((kc * 64 + skq * 16) ^ ((srow & 7) << 4));
        *reinterpret_cast<uint4*>((char*)aH + off) = *reinterpret_cast<uint4*>(hi2);
        *reinterpret_cast<uint4*>((char*)aL + off) = *reinterpret_cast<uint4*>(lo2);
    }
    __syncthreads();

    const int rt0 = rb >> 4;
    const int q   = lane >> 4;

    #pragma unroll 1
    for (int pass = 0; pass < 2; ++pass) {
        const int ct0 = w * 4 + pass * 2;

        v4f acc[4][2];
        #pragma unroll
        for (int i = 0; i < 4; i++)
            #pragma unroll
            for (int j = 0; j < 2; j++) acc[i][j] = (v4f){0.f, 0.f, 0.f, 0.f};

        #pragma unroll 4
        for (int kc = 0; kc < 8; ++kc) {
            v8s wh[2], wl[2];
            #pragma unroll
            for (int ntl = 0; ntl < 2; ntl++) {
                const size_t idx = ((size_t)((ct0 + ntl) * 8 + kc) * 64 + lane) * 8;
                wh[ntl] = *reinterpret_cast<const v8s*>(&WehHi[idx]);
                wl[ntl] = *reinterpret_cast<const v8s*>(&WehLo[idx]);
            }
            v8s ah[4], al[4];
            #pragma unroll
            for (int mt = 0; mt < 4; mt++) {
                const int row = mt * 16 + (lane & 15);
                const int off = row * 512 + ((kc * 64 + (lane >> 4) * 16) ^ ((row & 7) << 4));
                ah[mt] = *reinterpret_cast<const v8s*>((const char*)aH + off);
                al[mt] = *reinterpret_cast<const v8s*>((const char*)aL + off);
            }
            #pragma unroll
            for (int mt = 0; mt < 4; mt++) {
                #pragma unroll
                for (int ntl = 0; ntl < 2; ntl++) {
                    acc[mt][ntl] = __builtin_amdgcn_mfma_f32_16x16x32_bf16(wh[ntl], ah[mt], acc[mt][ntl], 0, 0, 0);
                    acc[mt][ntl] = __builtin_amdgcn_mfma_f32_16x16x32_bf16(wl[ntl], ah[mt], acc[mt][ntl], 0, 0, 0);
                    acc[mt][ntl] = __builtin_amdgcn_mfma_f32_16x16x32_bf16(wh[ntl], al[mt], acc[mt][ntl], 0, 0, 0);
                }
            }
        }
        // epilogue for this pass's 2 col-tiles (nt streaming stores)
        #pragma unroll
        for (int mt = 0; mt < 4; mt++) {
            #pragma unroll
            for (int ntl = 0; ntl < 2; ntl++) {
                const int ct = ct0 + ntl;
                const int c  = ct * 16 + q * 4;
                const float4 be = *reinterpret_cast<const float4*>(&b_eh[c]);
                float h0 = fmaxf(acc[mt][ntl][0] + be.x, 0.f);
                float h1 = fmaxf(acc[mt][ntl][1] + be.y, 0.f);
                float h2 = fmaxf(acc[mt][ntl][2] + be.z, 0.f);
                float h3 = fmaxf(acc[mt][ntl][3] + be.w, 0.f);
                unsigned short s0 = f2bf(h0), s1 = f2bf(h1), s2 = f2bf(h2), s3 = f2bf(h3);
                const unsigned phx = (unsigned)s0 | ((unsigned)s1 << 16);
                const unsigned phy = (unsigned)s2 | ((unsigned)s3 << 16);
                const unsigned plx = pack2(h0 - bf2f(s0), h1 - bf2f(s1));
                const unsigned ply = pack2(h2 - bf2f(s2), h3 - bf2f(s3));
                const int oct = ct * 2 + (q >> 1);
                const size_t base = (((size_t)(rt0 + mt) * 64 + oct) * 16 + (lane & 15)) * 8 + (q & 1) * 4;
                ntst_u2(&hHi[base], phx, phy);
                ntst_u2(&hLo[base], plx, ply);
            }
        }
    }
}

// ---------------- K2: pre_act (split-bf16 MFMA); top-5; gap-flag; outputs ----------------
// 128 rows/block; wave w owns row-tiles {2w, 2w+1}; W frags shared; nt h loads + nt output stores.
__global__ __launch_bounds__(256, 4)
void k_enc2_topk(const unsigned short* __restrict__ hHi,   // octet layout
                 const unsigned short* __restrict__ hLo,
                 const unsigned short* __restrict__ WeoHi,
                 const unsigned short* __restrict__ WeoLo,
                 const float* __restrict__ b_eo,
                 const float* __restrict__ lat_b,
                 float* __restrict__ pre_out,
                 float* __restrict__ mask_out,
                 float* __restrict__ sl_out,
                 int*   __restrict__ fcount,
                 int*   __restrict__ flist)
{
    __shared__ float pa[128][68];
    __shared__ unsigned long long mbits[128];
    const int t    = threadIdx.x;
    const int lane = t & 63;
    const int w    = t >> 6;
    const int rb   = blockIdx.x * 128;
    const int rtA  = (rb >> 4) + w * 2;
    const int rtB  = rtA + 1;

    v4f acc[2][4];
    #pragma unroll
    for (int s = 0; s < 2; s++)
        #pragma unroll
        for (int i = 0; i < 4; i++) acc[s][i] = (v4f){0.f, 0.f, 0.f, 0.f};

    #pragma unroll 4
    for (int kcl = 0; kcl < 16; ++kcl) {
        const size_t baseA = ((size_t)(rtA * 64 + kcl * 4 + (lane >> 4)) * 16 + (lane & 15)) * 8;
        const size_t baseB = ((size_t)(rtB * 64 + kcl * 4 + (lane >> 4)) * 16 + (lane & 15)) * 8;
        const v8s hhA = ntld_v8s(&hHi[baseA]);
        const v8s hlA = ntld_v8s(&hLo[baseA]);
        const v8s hhB = ntld_v8s(&hHi[baseB]);
        const v8s hlB = ntld_v8s(&hLo[baseB]);
        #pragma unroll
        for (int lt = 0; lt < 4; lt++) {
            const size_t idx = ((size_t)(lt * 16 + kcl) * 64 + lane) * 8;
            const v8s wh = *reinterpret_cast<const v8s*>(&WeoHi[idx]);
            const v8s wl = *reinterpret_cast<const v8s*>(&WeoLo[idx]);
            acc[0][lt] = __builtin_amdgcn_mfma_f32_16x16x32_bf16(wh, hhA, acc[0][lt], 0, 0, 0);
            acc[0][lt] = __builtin_amdgcn_mfma_f32_16x16x32_bf16(wl, hhA, acc[0][lt], 0, 0, 0);
            acc[0][lt] = __builtin_amdgcn_mfma_f32_16x16x32_bf16(wh, hlA, acc[0][lt], 0, 0, 0);
            acc[1][lt] = __builtin_amdgcn_mfma_f32_16x16x32_bf16(wh, hhB, acc[1][lt], 0, 0, 0);
            acc[1][lt] = __builtin_amdgcn_mfma_f32_16x16x32_bf16(wl, hhB, acc[1][lt], 0, 0, 0);
            acc[1][lt] = __builtin_amdgcn_mfma_f32_16x16x32_bf16(wh, hlB, acc[1][lt], 0, 0, 0);
        }
    }
    #pragma unroll
    for (int s = 0; s < 2; s++) {
        const int row = w * 32 + s * 16 + (lane & 15);
        #pragma unroll
        for (int lt = 0; lt < 4; lt++) {
            const int l0 = lt * 16 + ((lane >> 4) << 2);
            const float4 be = *reinterpret_cast<const float4*>(&b_eo[l0]);
            const float4 lb = *reinterpret_cast<const float4*>(&lat_b[l0]);
            float4 o;
            o.x = acc[s][lt][0] + be.x + lb.x;
            o.y = acc[s][lt][1] + be.y + lb.y;
            o.z = acc[s][lt][2] + be.z + lb.z;
            o.w = acc[s][lt][3] + be.w + lb.w;
            *reinterpret_cast<float4*>(&pa[row][l0]) = o;
        }
    }
    __syncthreads();
    if (t < 128) {
        int r = t;
        unsigned long long used = 0ULL;
        float bv[5];
        #pragma unroll
        for (int p = 0; p < 5; p++) {
            float best = -3.402823466e38f; int bidx = 0;
            for (int j = 0; j < 64; j++) {
                float v = pa[r][j];
                if (!((used >> j) & 1ULL) && v > best) { best = v; bidx = j; }
            }
            used |= 1ULL << bidx;
            bv[p] = best;
        }
        mbits[r] = used;
        float v6 = -3.402823466e38f;
        for (int j = 0; j < 64; j++) {
            float v = pa[r][j];
            if (!((used >> j) & 1ULL) && v > v6) v6 = v;
        }
        if (bv[4] - v6 < GAP_TAU) {
            int slot = atomicAdd(fcount, 1);
            flist[slot] = rb + r;
        }
    }
    __syncthreads();
    {
        const int c = (t & 15) * 4;
        #pragma unroll
        for (int pass = 0; pass < 8; pass++) {
            const int row = pass * 16 + (t >> 4);
            const size_t gr = (size_t)(rb + row);
            const unsigned long long bits = mbits[row];
            const float p0 = pa[row][c + 0], p1 = pa[row][c + 1];
            const float p2 = pa[row][c + 2], p3 = pa[row][c + 3];
            const float m0 = (float)((bits >> (c + 0)) & 1ULL);
            const float m1 = (float)((bits >> (c + 1)) & 1ULL);
            const float m2 = (float)((bits >> (c + 2)) & 1ULL);
            const float m3 = (float)((bits >> (c + 3)) & 1ULL);
            ntst_f4(&pre_out[gr * 64 + c],  p0, p1, p2, p3);
            ntst_f4(&mask_out[gr * 64 + c], m0, m1, m2, m3);
            ntst_f4(&sl_out[gr * 64 + c],   m0 * p0, m1 * p1, m2 * p2, m3 * p3);
        }
    }
}

// ---------------- K2b: fp32 exact repair of gap-flagged rows ----------------
__global__ __launch_bounds__(256)
void k_repair(const float* __restrict__ x,
              const float* __restrict__ pre_bias,
              const float* __restrict__ WehT,     // [256][512] fp32 transposed
              const float* __restrict__ b_eh,
              const float* __restrict__ WeoT,     // [512][64] fp32 transposed
              const float* __restrict__ b_eo,
              const float* __restrict__ lat_b,
              const int* __restrict__ fcount,
              const int* __restrict__ flist,
              float* __restrict__ pre_out,
              float* __restrict__ mask_out,
              float* __restrict__ sl_out)
{
    __shared__ float xs[256];
    __shared__ float hs[512];
    __shared__ float part[64][4];
    const int t = threadIdx.x;
    const int n = *fcount;
    #pragma unroll 1
    for (int it = blockIdx.x; it < n; it += gridDim.x) {
        const int r = flist[it];
        xs[t] = x[(size_t)r * 256 + t] - pre_bias[t];
        __syncthreads();
        {
            float a0 = 0.f, a1 = 0.f;
            #pragma unroll 8
            for (int k = 0; k < 256; ++k) {
                const float xk = xs[k];
                a0 = fmaf(WehT[(size_t)k * 512 + t], xk, a0);
                a1 = fmaf(WehT[(size_t)k * 512 + t + 256], xk, a1);
            }
            hs[t]       = fmaxf(a0 + b_eh[t], 0.f);
            hs[t + 256] = fmaxf(a1 + b_eh[t + 256], 0.f);
        }
        __syncthreads();
        {
            const int l = t & 63, q = t >> 6;
            float acc = 0.f;
            const int k0 = q * 128;
            #pragma unroll 8
            for (int k = k0; k < k0 + 128; ++k)
                acc = fmaf(WeoT[(size_t)k * 64 + l], hs[k], acc);
            part[l][q] = acc;
        }
        __syncthreads();
        if (t < 64) {
            const float v = ((part[t][0] + part[t][1]) + (part[t][2] + part[t][3]))
                            + b_eo[t] + lat_b[t];
            unsigned long long used = 0ULL;
            #pragma unroll
            for (int p = 0; p < 5; p++) {
                float cand = ((used >> t) & 1ULL) ? -3.402823466e38f : v;
                float m = cand;
                #pragma unroll
                for (int off = 1; off < 64; off <<= 1)
                    m = fmaxf(m, __shfl_xor(m, off));
                const unsigned long long msk = __ballot(cand == m);
                const int idx = __ffsll((long long)msk) - 1;
                used |= 1ULL << idx;
            }
            const size_t gr = (size_t)r;
            const float mb = (float)((used >> t) & 1ULL);
            pre_out[gr * 64 + t]  = v;
            mask_out[gr * 64 + t] = mb;
            sl_out[gr * 64 + t]   = mb * v;
        }
        __syncthreads();
    }
}

// ---------------- K3 phase 1: hd-tile GEMM (swapped operands -> A-frag-native D) ----------------
__device__ __forceinline__ void hd_phase1(unsigned short* __restrict__ buf,
                                          const unsigned short* __restrict__ slA,
                                          const unsigned short* __restrict__ WdhB,
                                          const float* __restrict__ b_dh,
                                          int c, int w, int lane)
{
    v4f ah[2][4];
    #pragma unroll
    for (int htl = 0; htl < 2; htl++) {
        const int h0 = (c * 8 + w * 2 + htl) * 16 + ((lane >> 4) << 2);
        const float4 bd = *reinterpret_cast<const float4*>(&b_dh[h0]);
        #pragma unroll
        for (int mt = 0; mt < 4; mt++) ah[htl][mt] = (v4f){bd.x, bd.y, bd.z, bd.w};
    }
    #pragma unroll
    for (int kc = 0; kc < 2; kc++) {
        v8s sa[4];
        #pragma unroll
        for (int mt = 0; mt < 4; mt++)
            sa[mt] = *reinterpret_cast<const v8s*>(&slA[((kc * 4 + mt) * 64 + lane) * 8]);
        #pragma unroll
        for (int htl = 0; htl < 2; htl++) {
            const int ht = c * 8 + w * 2 + htl;
            const v8s wb = *reinterpret_cast<const v8s*>(&WdhB[((size_t)(ht * 2 + kc) * 64 + lane) * 8]);
            #pragma unroll
            for (int mt = 0; mt < 4; mt++)
                ah[htl][mt] = __builtin_amdgcn_mfma_f32_16x16x32_bf16(wb, sa[mt], ah[htl][mt], 0, 0, 0);
        }
    }
    #pragma unroll
    for (int htl = 0; htl < 2; htl++) {
        const int hbase = (w * 2 + htl) * 16 + ((lane >> 4) << 2);
        const int kcgl  = hbase >> 5;
        const int lp    = (((hbase & 31) >> 3) << 4) + (lane & 15);
        const int ii    = hbase & 7;
        #pragma unroll
        for (int mt = 0; mt < 4; mt++) {
            uint2 o;
            o.x = pack2(fmaxf(ah[htl][mt][0], 0.f), fmaxf(ah[htl][mt][1], 0.f));
            o.y = pack2(fmaxf(ah[htl][mt][2], 0.f), fmaxf(ah[htl][mt][3], 0.f));
            *reinterpret_cast<uint2*>(&buf[((kcgl * 4 + mt) * 64 + lp) * 8 + ii]) = o;
        }
    }
}

// ---------------- K3: recon fully via MFMA, double-buffered hd, 1 barrier/chunk ----------------
__global__ __launch_bounds__(256)
void k_dec(const float* __restrict__ sl,              // [B][64] f32 (post-repair)
           const float* __restrict__ b_dh,            // [512]
           const unsigned short* __restrict__ WdhB,
           const unsigned short* __restrict__ Wdo_frag,
           const float* __restrict__ bias3,
           float* __restrict__ recon)                 // global [B][256]
{
    __shared__ __align__(16) unsigned short slA[2 * 4 * 64 * 8];      // 4 KB
    __shared__ __align__(16) unsigned short hdA[2][4 * 4 * 64 * 8];   // 2 x 16 KB
    const int t    = threadIdx.x;
    const int rb   = blockIdx.x * 64;
    const int lane = t & 63;
    const int w    = t >> 6;

    {
        const int row = t >> 2;
        const int seg = (t & 3) * 16;
        const float* sp = &sl[(size_t)(rb + row) * 64 + seg];
        const int mt = row >> 4;
        #pragma unroll
        for (int q = 0; q < 4; q++) {
            const fv4 v = ntld_f4(sp + q * 4);
            const float vals[4] = {v.x, v.y, v.z, v.w};
            #pragma unroll
            for (int e = 0; e < 4; e++) {
                const int k  = seg + q * 4 + e;
                const int kc = k >> 5;
                const int lp = ((k & 31) >> 3) * 16 + (row & 15);
                slA[((kc * 4 + mt) * 64 + lp) * 8 + (k & 7)] = f2bf(vals[e]);
            }
        }
    }
    __syncthreads();

    const int g  = w >> 1;      // main-GEMM row-group
    const int ch = w & 1;       // main-GEMM col-half

    v4f accM[2][8];
    #pragma unroll
    for (int s = 0; s < 2; s++)
        #pragma unroll
        for (int n = 0; n < 8; n++) accM[s][n] = (v4f){0.f, 0.f, 0.f, 0.f};

    hd_phase1(hdA[0], slA, WdhB, b_dh, 0, w, lane);
    __syncthreads();

    #pragma unroll 1
    for (int c = 0; c < 4; ++c) {
        if (c < 3)
            hd_phase1(hdA[(c + 1) & 1], slA, WdhB, b_dh, c + 1, w, lane);
        const unsigned short* buf = hdA[c & 1];
        #pragma unroll
        for (int kcgl = 0; kcgl < 4; ++kcgl) {
            const int kcg = c * 4 + kcgl;
            const v8s af0 = *reinterpret_cast<const v8s*>(&buf[((kcgl * 4 + g * 2 + 0) * 64 + lane) * 8]);
            const v8s af1 = *reinterpret_cast<const v8s*>(&buf[((kcgl * 4 + g * 2 + 1) * 64 + lane) * 8]);
            #pragma unroll
            for (int ntl = 0; ntl < 8; ntl++) {
                const int ntg = ch * 8 + ntl;
                const v8s bf = *reinterpret_cast<const v8s*>(
                    Wdo_frag + ((size_t)(ntg * 16 + kcg) * 64 + lane) * 8);
                accM[0][ntl] = __builtin_amdgcn_mfma_f32_16x16x32_bf16(af0, bf, accM[0][ntl], 0, 0, 0);
                accM[1][ntl] = __builtin_amdgcn_mfma_f32_16x16x32_bf16(af1, bf, accM[1][ntl], 0, 0, 0);
            }
        }
        __syncthreads();
    }
    #pragma unroll
    for (int s = 0; s < 2; s++) {
        const int rowbase = rb + (g * 2 + s) * 16;
        #pragma unroll
        for (int ntl = 0; ntl < 8; ntl++) {
            const int col = ch * 128 + ntl * 16 + (lane & 15);
            const float bz = bias3[col];
            #pragma unroll
            for (int j = 0; j < 4; j++) {
                const size_t row = (size_t)(rowbase + (lane >> 4) * 4 + j);
                __builtin_nontemporal_store(accM[s][ntl][j] + bz, &recon[row * 256 + col]);
            }
        }
    }
}

// ---------------- host ----------------
extern "C" void kernel_launch(void* const* d_in, const int* in_sizes, int n_in,
                              void* d_out, int out_size, void* d_ws, size_t ws_size,
                              hipStream_t stream)
{
    const float* x        = (const float*)d_in[0];
    const float* pre_bias = (const float*)d_in[1];
    const float* W_eh     = (const float*)d_in[2];
    const float* b_eh     = (const float*)d_in[3];
    const float* W_eo     = (const float*)d_in[4];
    const float* b_eo     = (const float*)d_in[5];
    const float* lat_b    = (const float*)d_in[6];
    const float* W_dh     = (const float*)d_in[7];
    const float* b_dh     = (const float*)d_in[8];
    const float* W_do     = (const float*)d_in[9];
    const float* b_do     = (const float*)d_in[10];
    const float* dec_b    = (const float*)d_in[11];

    float* out = (float*)d_out;
    float* recon_out = out;
    float* sl_out    = out + (size_t)B_TOT * 256;
    float* pre_out   = sl_out + (size_t)B_TOT * 64;
    float* mask_out  = pre_out + (size_t)B_TOT * 64;
    float* spars_out = mask_out + (size_t)B_TOT * 64;

    char* ws = (char*)d_ws;
    unsigned short* WdhB  = (unsigned short*)ws;            // 64 KB (of 128 KB slot)
    float* bias3          = (float*)(ws + 131072);
    unsigned short* WdoF  = (unsigned short*)(ws + 132096);
    unsigned short* WehHi = (unsigned short*)(ws + 394240);
    unsigned short* WehLo = (unsigned short*)(ws + 656384);
    unsigned short* WeoHi = (unsigned short*)(ws + 918528);
    unsigned short* WeoLo = (unsigned short*)(ws + 984064);
    int* fcount           = (int*)(ws + 1049600);
    int* flist            = (int*)(ws + 1049664);           // 512 KB
    float* WehT           = (float*)(ws + 1573952);         // 512 KB
    float* WeoT           = (float*)(ws + 2098240);         // 128 KB
    unsigned short* hHi   = (unsigned short*)(ws + 2229312);
    unsigned short* hLo   = hHi + (size_t)B_TOT * 512;

    k_prep<<<32, 256, 0, stream>>>(W_dh, b_do, dec_b, pre_bias, W_do, W_eh, W_eo,
                                   WdhB, bias3, WdoF, WehHi, WehLo, WeoHi, WeoLo,
                                   WehT, WeoT, spars_out, fcount);

    k_enc1<<<B_TOT / 64, 512, 0, stream>>>(x, pre_bias, WehHi, WehLo, b_eh, hHi, hLo);

    k_enc2_topk<<<B_TOT / 128, 256, 0, stream>>>(hHi, hLo, WeoHi, WeoLo, b_eo, lat_b,
                                                 pre_out, mask_out, sl_out,
                                                 fcount, flist);

    k_repair<<<1024, 256, 0, stream>>>(x, pre_bias, WehT, b_eh, WeoT, b_eo, lat_b,
                                       fcount, flist, pre_out, mask_out, sl_out);

    k_dec<<<B_TOT / 64, 256, 0, stream>>>(sl_out, b_dh, WdhB, WdoF, bias3, recon_out);
}

// Round 26
// 351.739 us; speedup vs baseline: 1.0463x; 1.0005x over previous
//
#include <hip/hip_runtime.h>
#include <hip/hip_bf16.h>
#include <stdint.h>

#define B_TOT 131072
#define GAP_TAU 2.5e-4f

typedef short v8s __attribute__((ext_vector_type(8)));
typedef float v4f __attribute__((ext_vector_type(4)));
typedef unsigned uv4 __attribute__((ext_vector_type(4)));
typedef unsigned uv2 __attribute__((ext_vector_type(2)));
typedef float fv4 __attribute__((ext_vector_type(4)));

__device__ __forceinline__ unsigned short f2bf(float f) {
    union { __hip_bfloat16 b; unsigned short s; } v;
    v.b = __float2bfloat16(f);
    return v.s;
}
__device__ __forceinline__ float bf2f(unsigned short s) {
    union { unsigned u; float f; } v; v.u = ((unsigned)s) << 16;
    return v.f;
}
__device__ __forceinline__ unsigned pack2(float lo, float hi) {
    return (unsigned)f2bf(lo) | ((unsigned)f2bf(hi) << 16);
}

// non-temporal helpers (pure cache hints; identical semantics)
__device__ __forceinline__ fv4 ntld_f4(const float* p) {
    return __builtin_nontemporal_load((const fv4*)p);
}
__device__ __forceinline__ v8s ntld_v8s(const unsigned short* p) {
    uv4 u = __builtin_nontemporal_load((const uv4*)p);
    union { uv4 u; v8s s; } c; c.u = u; return c.s;
}
__device__ __forceinline__ void ntst_f4(float* p, float x, float y, float z, float w) {
    fv4 f; f.x = x; f.y = y; f.z = z; f.w = w;
    __builtin_nontemporal_store(f, (fv4*)p);
}

// ---------------- K0: prep (weights swizzle + transposes + fcount zero) ----------------
__global__ void k_prep(const float* __restrict__ W_dh,      // [512][64]
                       const float* __restrict__ b_do,
                       const float* __restrict__ dec_b,
                       const float* __restrict__ pre_bias,
                       const float* __restrict__ W_do,
                       const float* __restrict__ W_eh,
                       const float* __restrict__ W_eo,
                       unsigned short* __restrict__ WdhB,    // hd-GEMM W-frags [32ht][2kc][64][8]
                       float* __restrict__ bias3,
                       unsigned short* __restrict__ Wdo_frag,
                       unsigned short* __restrict__ WehHi,
                       unsigned short* __restrict__ WehLo,
                       unsigned short* __restrict__ WeoHi,
                       unsigned short* __restrict__ WeoLo,
                       float* __restrict__ WehT,             // fp32 [256][512]
                       float* __restrict__ WeoT,             // fp32 [512][64]
                       float* __restrict__ spars_out,
                       int* __restrict__ fcount)
{
    int t = blockIdx.x * blockDim.x + threadIdx.x;
    int nthr = gridDim.x * blockDim.x;
    for (int g = t; g < 32 * 2 * 64; g += nthr) {
        int lane = g & 63;
        int rem = g >> 6;
        int kc = rem & 1, ht = rem >> 1;
        int h = ht * 16 + (lane & 15);
        int l = kc * 32 + (lane >> 4) * 8;
        const float* src = &W_dh[(size_t)h * 64 + l];
        unsigned short* dst = &WdhB[(size_t)g * 8];
        #pragma unroll
        for (int i = 0; i < 8; i++) dst[i] = f2bf(src[i]);
    }
    for (int g = t; g < 16384; g += nthr) {     // Wdo B-frag
        int lane = g & 63;
        int q = g >> 6;
        int nt = q >> 4, kc = q & 15;
        int col = nt * 16 + (lane & 15);
        int kbase = kc * 32 + (lane >> 4) * 8;
        const float* src = &W_do[(size_t)col * 512 + kbase];
        unsigned short* dst = &Wdo_frag[(size_t)g * 8];
        #pragma unroll
        for (int i = 0; i < 8; i++) dst[i] = f2bf(src[i]);
    }
    for (int g = t; g < 32 * 8 * 64; g += nthr) {   // W_eh hi/lo A-frag
        int lane = g & 63;
        int rem = g >> 6;
        int kcg = rem & 7, ct = rem >> 3;
        int c = ct * 16 + (lane & 15);
        int k = kcg * 32 + (lane >> 4) * 8;
        const float* src = &W_eh[(size_t)c * 256 + k];
        #pragma unroll
        for (int i = 0; i < 8; i++) {
            unsigned short hi = f2bf(src[i]);
            WehHi[(size_t)g * 8 + i] = hi;
            WehLo[(size_t)g * 8 + i] = f2bf(src[i] - bf2f(hi));
        }
    }
    for (int g = t; g < 4 * 16 * 64; g += nthr) {   // W_eo hi/lo A-frag
        int lane = g & 63;
        int rem = g >> 6;
        int kcg = rem & 15, lt = rem >> 4;
        int l = lt * 16 + (lane & 15);
        int k = kcg * 32 + (lane >> 4) * 8;
        const float* src = &W_eo[(size_t)l * 512 + k];
        #pragma unroll
        for (int i = 0; i < 8; i++) {
            unsigned short hi = f2bf(src[i]);
            WeoHi[(size_t)g * 8 + i] = hi;
            WeoLo[(size_t)g * 8 + i] = f2bf(src[i] - bf2f(hi));
        }
    }
    for (int i = t; i < 256 * 512; i += nthr) {     // WehT[k][j] = W_eh[j][k]
        int k = i >> 9, j = i & 511;
        WehT[i] = W_eh[(size_t)j * 256 + k];
    }
    for (int i = t; i < 512 * 64; i += nthr) {      // WeoT[k][l] = W_eo[l][k]
        int k = i >> 6, l = i & 63;
        WeoT[i] = W_eo[(size_t)l * 512 + k];
    }
    if (t < 256) bias3[t] = b_do[t] + dec_b[t] + pre_bias[t];
    if (t == 0) { spars_out[0] = 5.0f / 64.0f; *fcount = 0; }
}

// h planes OCTET layout: element H(row,k) = ((rowtile*64 + k/8)*16 + row%16)*8 + k%8

// ---------------- K1: h = relu((x-pb) @ W_eh^T + b_eh), split-bf16 MFMA ----------------
// 2-pass column split; nt x-loads; h-stores CACHED (L3 retention for enc2's reversed sweep).
__global__ __launch_bounds__(512, 4)
void k_enc1(const float* __restrict__ x,
            const float* __restrict__ pre_bias,
            const unsigned short* __restrict__ WehHi,
            const unsigned short* __restrict__ WehLo,
            const float* __restrict__ b_eh,
            unsigned short* __restrict__ hHi,   // octet layout
            unsigned short* __restrict__ hLo)
{
    __shared__ __align__(16) unsigned short aH[64 * 256];  // 32 KB, swizzled rows
    __shared__ __align__(16) unsigned short aL[64 * 256];  // 32 KB
    const int t    = threadIdx.x;
    const int lane = t & 63;
    const int w    = t >> 6;        // 0..7
    const int rb   = blockIdx.x * 64;

    #pragma unroll
    for (int i = 0; i < 4; i++) {
        const int f    = t + i * 512;       // 0..2047
        const int srow = f >> 5;            // 0..63
        const int kc   = (f >> 2) & 7;      // 0..7
        const int skq  = f & 3;             // 0..3
        const float* xp = &x[(size_t)(rb + srow) * 256 + kc * 32 + skq * 8];
        const float* pp = &pre_bias[kc * 32 + skq * 8];
        const fv4 v0 = ntld_f4(xp);
        const fv4 v1 = ntld_f4(xp + 4);
        const float4 p0 = *reinterpret_cast<const float4*>(pp);
        const float4 p1 = *reinterpret_cast<const float4*>(pp + 4);
        float fv[8] = {v0.x - p0.x, v0.y - p0.y, v0.z - p0.z, v0.w - p0.w,
                       v1.x - p1.x, v1.y - p1.y, v1.z - p1.z, v1.w - p1.w};
        unsigned hi2[4], lo2[4];
        #pragma unroll
        for (int q = 0; q < 4; q++) {
            unsigned short h0 = f2bf(fv[q * 2]), h1 = f2bf(fv[q * 2 + 1]);
            hi2[q] = (unsigned)h0 | ((unsigned)h1 << 16);
            lo2[q] = pack2(fv[q * 2] - bf2f(h0), fv[q * 2 + 1] - bf2f(h1));
        }
        const int off = srow * 512 + ((kc * 64 + skq * 16) ^ ((srow & 7) << 4));
        *reinterpret_cast<uint4*>((char*)aH + off) = *reinterpret_cast<uint4*>(hi2);
        *reinterpret_cast<uint4*>((char*)aL + off) = *reinterpret_cast<uint4*>(lo2);
    }
    __syncthreads();

    const int rt0 = rb >> 4;
    const int q   = lane >> 4;

    #pragma unroll 1
    for (int pass = 0; pass < 2; ++pass) {
        const int ct0 = w * 4 + pass * 2;

        v4f acc[4][2];
        #pragma unroll
        for (int i = 0; i < 4; i++)
            #pragma unroll
            for (int j = 0; j < 2; j++) acc[i][j] = (v4f){0.f, 0.f, 0.f, 0.f};

        #pragma unroll 4
        for (int kc = 0; kc < 8; ++kc) {
            v8s wh[2], wl[2];
            #pragma unroll
            for (int ntl = 0; ntl < 2; ntl++) {
                const size_t idx = ((size_t)((ct0 + ntl) * 8 + kc) * 64 + lane) * 8;
                wh[ntl] = *reinterpret_cast<const v8s*>(&WehHi[idx]);
                wl[ntl] = *reinterpret_cast<const v8s*>(&WehLo[idx]);
            }
            v8s ah[4], al[4];
            #pragma unroll
            for (int mt = 0; mt < 4; mt++) {
                const int row = mt * 16 + (lane & 15);
                const int off = row * 512 + ((kc * 64 + (lane >> 4) * 16) ^ ((row & 7) << 4));
                ah[mt] = *reinterpret_cast<const v8s*>((const char*)aH + off);
                al[mt] = *reinterpret_cast<const v8s*>((const char*)aL + off);
            }
            #pragma unroll
            for (int mt = 0; mt < 4; mt++) {
                #pragma unroll
                for (int ntl = 0; ntl < 2; ntl++) {
                    acc[mt][ntl] = __builtin_amdgcn_mfma_f32_16x16x32_bf16(wh[ntl], ah[mt], acc[mt][ntl], 0, 0, 0);
                    acc[mt][ntl] = __builtin_amdgcn_mfma_f32_16x16x32_bf16(wl[ntl], ah[mt], acc[mt][ntl], 0, 0, 0);
                    acc[mt][ntl] = __builtin_amdgcn_mfma_f32_16x16x32_bf16(wh[ntl], al[mt], acc[mt][ntl], 0, 0, 0);
                }
            }
        }
        // epilogue for this pass's 2 col-tiles (CACHED stores -> L3 retention)
        #pragma unroll
        for (int mt = 0; mt < 4; mt++) {
            #pragma unroll
            for (int ntl = 0; ntl < 2; ntl++) {
                const int ct = ct0 + ntl;
                const int c  = ct * 16 + q * 4;
                const float4 be = *reinterpret_cast<const float4*>(&b_eh[c]);
                float h0 = fmaxf(acc[mt][ntl][0] + be.x, 0.f);
                float h1 = fmaxf(acc[mt][ntl][1] + be.y, 0.f);
                float h2 = fmaxf(acc[mt][ntl][2] + be.z, 0.f);
                float h3 = fmaxf(acc[mt][ntl][3] + be.w, 0.f);
                unsigned short s0 = f2bf(h0), s1 = f2bf(h1), s2 = f2bf(h2), s3 = f2bf(h3);
                uint2 phi = { (unsigned)s0 | ((unsigned)s1 << 16), (unsigned)s2 | ((unsigned)s3 << 16) };
                uint2 plo = { pack2(h0 - bf2f(s0), h1 - bf2f(s1)),
                              pack2(h2 - bf2f(s2), h3 - bf2f(s3)) };
                const int oct = ct * 2 + (q >> 1);
                const size_t base = (((size_t)(rt0 + mt) * 64 + oct) * 16 + (lane & 15)) * 8 + (q & 1) * 4;
                *reinterpret_cast<uint2*>(&hHi[base]) = phi;
                *reinterpret_cast<uint2*>(&hLo[base]) = plo;
            }
        }
    }
}

// ---------------- K2: pre_act (split-bf16 MFMA); top-5; gap-flag; outputs ----------------
// 128 rows/block; REVERSED block->row mapping (newest h rows read first, L3-hot);
// wave w owns row-tiles {2w, 2w+1}; W frags shared; nt h loads + nt output stores.
__global__ __launch_bounds__(256, 4)
void k_enc2_topk(const unsigned short* __restrict__ hHi,   // octet layout
                 const unsigned short* __restrict__ hLo,
                 const unsigned short* __restrict__ WeoHi,
                 const unsigned short* __restrict__ WeoLo,
                 const float* __restrict__ b_eo,
                 const float* __restrict__ lat_b,
                 float* __restrict__ pre_out,
                 float* __restrict__ mask_out,
                 float* __restrict__ sl_out,
                 int*   __restrict__ fcount,
                 int*   __restrict__ flist)
{
    __shared__ float pa[128][68];
    __shared__ unsigned long long mbits[128];
    const int t    = threadIdx.x;
    const int lane = t & 63;
    const int w    = t >> 6;
    const int rb   = ((int)gridDim.x - 1 - (int)blockIdx.x) * 128;   // reversed sweep
    const int rtA  = (rb >> 4) + w * 2;
    const int rtB  = rtA + 1;

    v4f acc[2][4];
    #pragma unroll
    for (int s = 0; s < 2; s++)
        #pragma unroll
        for (int i = 0; i < 4; i++) acc[s][i] = (v4f){0.f, 0.f, 0.f, 0.f};

    #pragma unroll 4
    for (int kcl = 0; kcl < 16; ++kcl) {
        const size_t baseA = ((size_t)(rtA * 64 + kcl * 4 + (lane >> 4)) * 16 + (lane & 15)) * 8;
        const size_t baseB = ((size_t)(rtB * 64 + kcl * 4 + (lane >> 4)) * 16 + (lane & 15)) * 8;
        const v8s hhA = ntld_v8s(&hHi[baseA]);
        const v8s hlA = ntld_v8s(&hLo[baseA]);
        const v8s hhB = ntld_v8s(&hHi[baseB]);
        const v8s hlB = ntld_v8s(&hLo[baseB]);
        #pragma unroll
        for (int lt = 0; lt < 4; lt++) {
            const size_t idx = ((size_t)(lt * 16 + kcl) * 64 + lane) * 8;
            const v8s wh = *reinterpret_cast<const v8s*>(&WeoHi[idx]);
            const v8s wl = *reinterpret_cast<const v8s*>(&WeoLo[idx]);
            acc[0][lt] = __builtin_amdgcn_mfma_f32_16x16x32_bf16(wh, hhA, acc[0][lt], 0, 0, 0);
            acc[0][lt] = __builtin_amdgcn_mfma_f32_16x16x32_bf16(wl, hhA, acc[0][lt], 0, 0, 0);
            acc[0][lt] = __builtin_amdgcn_mfma_f32_16x16x32_bf16(wh, hlA, acc[0][lt], 0, 0, 0);
            acc[1][lt] = __builtin_amdgcn_mfma_f32_16x16x32_bf16(wh, hhB, acc[1][lt], 0, 0, 0);
            acc[1][lt] = __builtin_amdgcn_mfma_f32_16x16x32_bf16(wl, hhB, acc[1][lt], 0, 0, 0);
            acc[1][lt] = __builtin_amdgcn_mfma_f32_16x16x32_bf16(wh, hlB, acc[1][lt], 0, 0, 0);
        }
    }
    #pragma unroll
    for (int s = 0; s < 2; s++) {
        const int row = w * 32 + s * 16 + (lane & 15);
        #pragma unroll
        for (int lt = 0; lt < 4; lt++) {
            const int l0 = lt * 16 + ((lane >> 4) << 2);
            const float4 be = *reinterpret_cast<const float4*>(&b_eo[l0]);
            const float4 lb = *reinterpret_cast<const float4*>(&lat_b[l0]);
            float4 o;
            o.x = acc[s][lt][0] + be.x + lb.x;
            o.y = acc[s][lt][1] + be.y + lb.y;
            o.z = acc[s][lt][2] + be.z + lb.z;
            o.w = acc[s][lt][3] + be.w + lb.w;
            *reinterpret_cast<float4*>(&pa[row][l0]) = o;
        }
    }
    __syncthreads();
    if (t < 128) {
        int r = t;
        unsigned long long used = 0ULL;
        float bv[5];
        #pragma unroll
        for (int p = 0; p < 5; p++) {
            float best = -3.402823466e38f; int bidx = 0;
            for (int j = 0; j < 64; j++) {
                float v = pa[r][j];
                if (!((used >> j) & 1ULL) && v > best) { best = v; bidx = j; }
            }
            used |= 1ULL << bidx;
            bv[p] = best;
        }
        mbits[r] = used;
        float v6 = -3.402823466e38f;
        for (int j = 0; j < 64; j++) {
            float v = pa[r][j];
            if (!((used >> j) & 1ULL) && v > v6) v6 = v;
        }
        if (bv[4] - v6 < GAP_TAU) {
            int slot = atomicAdd(fcount, 1);
            flist[slot] = rb + r;
        }
    }
    __syncthreads();
    {
        const int c = (t & 15) * 4;
        #pragma unroll
        for (int pass = 0; pass < 8; pass++) {
            const int row = pass * 16 + (t >> 4);
            const size_t gr = (size_t)(rb + row);
            const unsigned long long bits = mbits[row];
            const float p0 = pa[row][c + 0], p1 = pa[row][c + 1];
            const float p2 = pa[row][c + 2], p3 = pa[row][c + 3];
            const float m0 = (float)((bits >> (c + 0)) & 1ULL);
            const float m1 = (float)((bits >> (c + 1)) & 1ULL);
            const float m2 = (float)((bits >> (c + 2)) & 1ULL);
            const float m3 = (float)((bits >> (c + 3)) & 1ULL);
            ntst_f4(&pre_out[gr * 64 + c],  p0, p1, p2, p3);
            ntst_f4(&mask_out[gr * 64 + c], m0, m1, m2, m3);
            ntst_f4(&sl_out[gr * 64 + c],   m0 * p0, m1 * p1, m2 * p2, m3 * p3);
        }
    }
}

// ---------------- K2b: fp32 exact repair of gap-flagged rows ----------------
__global__ __launch_bounds__(256)
void k_repair(const float* __restrict__ x,
              const float* __restrict__ pre_bias,
              const float* __restrict__ WehT,     // [256][512] fp32 transposed
              const float* __restrict__ b_eh,
              const float* __restrict__ WeoT,     // [512][64] fp32 transposed
              const float* __restrict__ b_eo,
              const float* __restrict__ lat_b,
              const int* __restrict__ fcount,
              const int* __restrict__ flist,
              float* __restrict__ pre_out,
              float* __restrict__ mask_out,
              float* __restrict__ sl_out)
{
    __shared__ float xs[256];
    __shared__ float hs[512];
    __shared__ float part[64][4];
    const int t = threadIdx.x;
    const int n = *fcount;
    #pragma unroll 1
    for (int it = blockIdx.x; it < n; it += gridDim.x) {
        const int r = flist[it];
        xs[t] = x[(size_t)r * 256 + t] - pre_bias[t];
        __syncthreads();
        {
            float a0 = 0.f, a1 = 0.f;
            #pragma unroll 8
            for (int k = 0; k < 256; ++k) {
                const float xk = xs[k];
                a0 = fmaf(WehT[(size_t)k * 512 + t], xk, a0);
                a1 = fmaf(WehT[(size_t)k * 512 + t + 256], xk, a1);
            }
            hs[t]       = fmaxf(a0 + b_eh[t], 0.f);
            hs[t + 256] = fmaxf(a1 + b_eh[t + 256], 0.f);
        }
        __syncthreads();
        {
            const int l = t & 63, q = t >> 6;
            float acc = 0.f;
            const int k0 = q * 128;
            #pragma unroll 8
            for (int k = k0; k < k0 + 128; ++k)
                acc = fmaf(WeoT[(size_t)k * 64 + l], hs[k], acc);
            part[l][q] = acc;
        }
        __syncthreads();
        if (t < 64) {
            const float v = ((part[t][0] + part[t][1]) + (part[t][2] + part[t][3]))
                            + b_eo[t] + lat_b[t];
            unsigned long long used = 0ULL;
            #pragma unroll
            for (int p = 0; p < 5; p++) {
                float cand = ((used >> t) & 1ULL) ? -3.402823466e38f : v;
                float m = cand;
                #pragma unroll
                for (int off = 1; off < 64; off <<= 1)
                    m = fmaxf(m, __shfl_xor(m, off));
                const unsigned long long msk = __ballot(cand == m);
                const int idx = __ffsll((long long)msk) - 1;
                used |= 1ULL << idx;
            }
            const size_t gr = (size_t)r;
            const float mb = (float)((used >> t) & 1ULL);
            pre_out[gr * 64 + t]  = v;
            mask_out[gr * 64 + t] = mb;
            sl_out[gr * 64 + t]   = mb * v;
        }
        __syncthreads();
    }
}

// ---------------- K3 phase 1: hd-tile GEMM (swapped operands -> A-frag-native D) ----------------
__device__ __forceinline__ void hd_phase1(unsigned short* __restrict__ buf,
                                          const unsigned short* __restrict__ slA,
                                          const unsigned short* __restrict__ WdhB,
                                          const float* __restrict__ b_dh,
                                          int c, int w, int lane)
{
    v4f ah[2][4];
    #pragma unroll
    for (int htl = 0; htl < 2; htl++) {
        const int h0 = (c * 8 + w * 2 + htl) * 16 + ((lane >> 4) << 2);
        const float4 bd = *reinterpret_cast<const float4*>(&b_dh[h0]);
        #pragma unroll
        for (int mt = 0; mt < 4; mt++) ah[htl][mt] = (v4f){bd.x, bd.y, bd.z, bd.w};
    }
    #pragma unroll
    for (int kc = 0; kc < 2; kc++) {
        v8s sa[4];
        #pragma unroll
        for (int mt = 0; mt < 4; mt++)
            sa[mt] = *reinterpret_cast<const v8s*>(&slA[((kc * 4 + mt) * 64 + lane) * 8]);
        #pragma unroll
        for (int htl = 0; htl < 2; htl++) {
            const int ht = c * 8 + w * 2 + htl;
            const v8s wb = *reinterpret_cast<const v8s*>(&WdhB[((size_t)(ht * 2 + kc) * 64 + lane) * 8]);
            #pragma unroll
            for (int mt = 0; mt < 4; mt++)
                ah[htl][mt] = __builtin_amdgcn_mfma_f32_16x16x32_bf16(wb, sa[mt], ah[htl][mt], 0, 0, 0);
        }
    }
    #pragma unroll
    for (int htl = 0; htl < 2; htl++) {
        const int hbase = (w * 2 + htl) * 16 + ((lane >> 4) << 2);
        const int kcgl  = hbase >> 5;
        const int lp    = (((hbase & 31) >> 3) << 4) + (lane & 15);
        const int ii    = hbase & 7;
        #pragma unroll
        for (int mt = 0; mt < 4; mt++) {
            uint2 o;
            o.x = pack2(fmaxf(ah[htl][mt][0], 0.f), fmaxf(ah[htl][mt][1], 0.f));
            o.y = pack2(fmaxf(ah[htl][mt][2], 0.f), fmaxf(ah[htl][mt][3], 0.f));
            *reinterpret_cast<uint2*>(&buf[((kcgl * 4 + mt) * 64 + lp) * 8 + ii]) = o;
        }
    }
}

// ---------------- K3: recon fully via MFMA, double-buffered hd, 1 barrier/chunk ----------------
__global__ __launch_bounds__(256)
void k_dec(const float* __restrict__ sl,              // [B][64] f32 (post-repair)
           const float* __restrict__ b_dh,            // [512]
           const unsigned short* __restrict__ WdhB,
           const unsigned short* __restrict__ Wdo_frag,
           const float* __restrict__ bias3,
           float* __restrict__ recon)                 // global [B][256]
{
    __shared__ __align__(16) unsigned short slA[2 * 4 * 64 * 8];      // 4 KB
    __shared__ __align__(16) unsigned short hdA[2][4 * 4 * 64 * 8];   // 2 x 16 KB
    const int t    = threadIdx.x;
    const int rb   = blockIdx.x * 64;
    const int lane = t & 63;
    const int w    = t >> 6;

    {
        const int row = t >> 2;
        const int seg = (t & 3) * 16;
        const float* sp = &sl[(size_t)(rb + row) * 64 + seg];
        const int mt = row >> 4;
        #pragma unroll
        for (int q = 0; q < 4; q++) {
            const fv4 v = ntld_f4(sp + q * 4);
            const float vals[4] = {v.x, v.y, v.z, v.w};
            #pragma unroll
            for (int e = 0; e < 4; e++) {
                const int k  = seg + q * 4 + e;
                const int kc = k >> 5;
                const int lp = ((k & 31) >> 3) * 16 + (row & 15);
                slA[((kc * 4 + mt) * 64 + lp) * 8 + (k & 7)] = f2bf(vals[e]);
            }
        }
    }
    __syncthreads();

    const int g  = w >> 1;      // main-GEMM row-group
    const int ch = w & 1;       // main-GEMM col-half

    v4f accM[2][8];
    #pragma unroll
    for (int s = 0; s < 2; s++)
        #pragma unroll
        for (int n = 0; n < 8; n++) accM[s][n] = (v4f){0.f, 0.f, 0.f, 0.f};

    hd_phase1(hdA[0], slA, WdhB, b_dh, 0, w, lane);
    __syncthreads();

    #pragma unroll 1
    for (int c = 0; c < 4; ++c) {
        if (c < 3)
            hd_phase1(hdA[(c + 1) & 1], slA, WdhB, b_dh, c + 1, w, lane);
        const unsigned short* buf = hdA[c & 1];
        #pragma unroll
        for (int kcgl = 0; kcgl < 4; ++kcgl) {
            const int kcg = c * 4 + kcgl;
            const v8s af0 = *reinterpret_cast<const v8s*>(&buf[((kcgl * 4 + g * 2 + 0) * 64 + lane) * 8]);
            const v8s af1 = *reinterpret_cast<const v8s*>(&buf[((kcgl * 4 + g * 2 + 1) * 64 + lane) * 8]);
            #pragma unroll
            for (int ntl = 0; ntl < 8; ntl++) {
                const int ntg = ch * 8 + ntl;
                const v8s bf = *reinterpret_cast<const v8s*>(
                    Wdo_frag + ((size_t)(ntg * 16 + kcg) * 64 + lane) * 8);
                accM[0][ntl] = __builtin_amdgcn_mfma_f32_16x16x32_bf16(af0, bf, accM[0][ntl], 0, 0, 0);
                accM[1][ntl] = __builtin_amdgcn_mfma_f32_16x16x32_bf16(af1, bf, accM[1][ntl], 0, 0, 0);
            }
        }
        __syncthreads();
    }
    #pragma unroll
    for (int s = 0; s < 2; s++) {
        const int rowbase = rb + (g * 2 + s) * 16;
        #pragma unroll
        for (int ntl = 0; ntl < 8; ntl++) {
            const int col = ch * 128 + ntl * 16 + (lane & 15);
            const float bz = bias3[col];
            #pragma unroll
            for (int j = 0; j < 4; j++) {
                const size_t row = (size_t)(rowbase + (lane >> 4) * 4 + j);
                __builtin_nontemporal_store(accM[s][ntl][j] + bz, &recon[row * 256 + col]);
            }
        }
    }
}

// ---------------- host ----------------
extern "C" void kernel_launch(void* const* d_in, const int* in_sizes, int n_in,
                              void* d_out, int out_size, void* d_ws, size_t ws_size,
                              hipStream_t stream)
{
    const float* x        = (const float*)d_in[0];
    const float* pre_bias = (const float*)d_in[1];
    const float* W_eh     = (const float*)d_in[2];
    const float* b_eh     = (const float*)d_in[3];
    const float* W_eo     = (const float*)d_in[4];
    const float* b_eo     = (const float*)d_in[5];
    const float* lat_b    = (const float*)d_in[6];
    const float* W_dh     = (const float*)d_in[7];
    const float* b_dh     = (const float*)d_in[8];
    const float* W_do     = (const float*)d_in[9];
    const float* b_do     = (const float*)d_in[10];
    const float* dec_b    = (const float*)d_in[11];

    float* out = (float*)d_out;
    float* recon_out = out;
    float* sl_out    = out + (size_t)B_TOT * 256;
    float* pre_out   = sl_out + (size_t)B_TOT * 64;
    float* mask_out  = pre_out + (size_t)B_TOT * 64;
    float* spars_out = mask_out + (size_t)B_TOT * 64;

    char* ws = (char*)d_ws;
    unsigned short* WdhB  = (unsigned short*)ws;            // 64 KB (of 128 KB slot)
    float* bias3          = (float*)(ws + 131072);
    unsigned short* WdoF  = (unsigned short*)(ws + 132096);
    unsigned short* WehHi = (unsigned short*)(ws + 394240);
    unsigned short* WehLo = (unsigned short*)(ws + 656384);
    unsigned short* WeoHi = (unsigned short*)(ws + 918528);
    unsigned short* WeoLo = (unsigned short*)(ws + 984064);
    int* fcount           = (int*)(ws + 1049600);
    int* flist            = (int*)(ws + 1049664);           // 512 KB
    float* WehT           = (float*)(ws + 1573952);         // 512 KB
    float* WeoT           = (float*)(ws + 2098240);         // 128 KB
    unsigned short* hHi   = (unsigned short*)(ws + 2229312);
    unsigned short* hLo   = hHi + (size_t)B_TOT * 512;

    k_prep<<<32, 256, 0, stream>>>(W_dh, b_do, dec_b, pre_bias, W_do, W_eh, W_eo,
                                   WdhB, bias3, WdoF, WehHi, WehLo, WeoHi, WeoLo,
                                   WehT, WeoT, spars_out, fcount);

    k_enc1<<<B_TOT / 64, 512, 0, stream>>>(x, pre_bias, WehHi, WehLo, b_eh, hHi, hLo);

    k_enc2_topk<<<B_TOT / 128, 256, 0, stream>>>(hHi, hLo, WeoHi, WeoLo, b_eo, lat_b,
                                                 pre_out, mask_out, sl_out,
                                                 fcount, flist);

    k_repair<<<1024, 256, 0, stream>>>(x, pre_bias, WehT, b_eh, WeoT, b_eo, lat_b,
                                       fcount, flist, pre_out, mask_out, sl_out);

    k_dec<<<B_TOT / 64, 256, 0, stream>>>(sl_out, b_dh, WdhB, WdoF, bias3, recon_out);
}